// Round 3
// baseline (92.194 us; speedup 1.0000x reference)
//
#include <hip/hip_runtime.h>

// LIF recurrence: mem = 0.9*mem + x; spike = (mem >= 1); record; mem -= spike.
// T=20, elementwise-independent. Output: [spikes T*N][mems T*N], fp32.
//
// R3: T split into TCHUNKS=4 chunks of 5 steps. Each thread recomputes the
// recurrence from t=0 (bit-exact, ~20 fmul+fadd+cmp -- negligible) but stores
// only its chunk's planes. 4x wave count -> 4x independent store streams to
// fix the ~2.4 TB/s effective write BW (fill achieves 6.2 TB/s on same box).
//
// Numerics: forced mul-then-add (__fmul_rn/__fadd_rn), no FMA contraction --
// 1-ulp drift flips the >=1.0 threshold (absmax=1.0 failure mode).

#define TSTEPS 20
#define TCHUNKS 4
#define TPER (TSTEPS / TCHUNKS)   // 5

typedef float v4f __attribute__((ext_vector_type(4)));

__global__ __launch_bounds__(256) void
TemporalEncoding_57672820850797_kernel(const v4f* __restrict__ x,
                                       float* __restrict__ out, int n4) {
    int gid = blockIdx.x * blockDim.x + threadIdx.x;
    int i = gid & (131072 - 1);          // float4 index within plane (n4 = 131072)
    int chunk = gid >> 17;               // which 5-step slice this thread stores
    if (i >= n4) return;

    const v4f xv = __builtin_nontemporal_load(&x[i]);
    const int t_lo = chunk * TPER;
    const int t_hi = t_lo + TPER;

    v4f* __restrict__ spikes = reinterpret_cast<v4f*>(out) + (size_t)t_lo * n4 + i;
    v4f* __restrict__ mems   = reinterpret_cast<v4f*>(out) + (size_t)(TSTEPS + t_lo) * n4 + i;

    float m0 = 0.f, m1 = 0.f, m2 = 0.f, m3 = 0.f;

#pragma unroll
    for (int t = 0; t < TSTEPS; ++t) {
        if (t >= t_hi) break;
        // mem = 0.9*mem + x (separate rounding steps, matches numpy exactly)
        m0 = __fadd_rn(__fmul_rn(0.9f, m0), xv.x);
        m1 = __fadd_rn(__fmul_rn(0.9f, m1), xv.y);
        m2 = __fadd_rn(__fmul_rn(0.9f, m2), xv.z);
        m3 = __fadd_rn(__fmul_rn(0.9f, m3), xv.w);

        float s0 = (m0 >= 1.0f) ? 1.0f : 0.0f;
        float s1 = (m1 >= 1.0f) ? 1.0f : 0.0f;
        float s2 = (m2 >= 1.0f) ? 1.0f : 0.0f;
        float s3 = (m3 >= 1.0f) ? 1.0f : 0.0f;

        if (t >= t_lo) {
            v4f sv; sv.x = s0; sv.y = s1; sv.z = s2; sv.w = s3;
            v4f mv; mv.x = m0; mv.y = m1; mv.z = m2; mv.w = m3;
            __builtin_nontemporal_store(sv, spikes);
            __builtin_nontemporal_store(mv, mems);
            spikes += n4;
            mems   += n4;
        }

        m0 -= s0;
        m1 -= s1;
        m2 -= s2;
        m3 -= s3;
    }
}

extern "C" void kernel_launch(void* const* d_in, const int* in_sizes, int n_in,
                              void* d_out, int out_size, void* d_ws, size_t ws_size,
                              hipStream_t stream) {
    const float* x = (const float*)d_in[0];
    float* out = (float*)d_out;
    const int n = in_sizes[0];       // 64*8192 = 524288
    const int n4 = n / 4;            // 131072 float4 lanes per plane
    const int block = 256;
    const int grid = (n4 * TCHUNKS + block - 1) / block;  // 2048 blocks
    TemporalEncoding_57672820850797_kernel<<<grid, block, 0, stream>>>(
        (const v4f*)x, out, n4);
}